// Round 7
// baseline (556.474 us; speedup 1.0000x reference)
//
#include <hip/hip_runtime.h>
#include <hip/hip_bf16.h>

#define N_NODES 100000
#define N_EDGES 1600000
#define CAP 64  // bucket capacity; deg ~ Poisson(16), P(deg>=64) ~ 1e-20

typedef __attribute__((ext_vector_type(8))) short bf16x8;
typedef __attribute__((ext_vector_type(4))) float f32x4;

__device__ __forceinline__ float bflo(uint u) { return __builtin_bit_cast(float, u << 16); }
__device__ __forceinline__ float bfhi(uint u) { return __builtin_bit_cast(float, u & 0xffff0000u); }
__device__ __forceinline__ ushort f2bf(float f) {
    union { ushort u; __hip_bfloat16 b; } c;
    c.b = __float2bfloat16(f);
    return c.u;
}

// ---------------------------------------------------------------------------
// Bucket fill — EXACT R3 version (known-pass). R5/R6 delta (CAP=48, guards,
// i32x4 loads, deep unrolls) produced 1.06 absmax; this round bisects.
// After this, cursor[d] == degree(d).
// ---------------------------------------------------------------------------
__global__ __launch_bounds__(256) void bucket_fill_kernel(
    const int* __restrict__ src, const int* __restrict__ dst,
    int* __restrict__ cursor, int* __restrict__ buckets) {
    int b = blockIdx.x;          // 1024 blocks
    int xcd = b & 7;
    int gb = b >> 3;             // 0..127 within xcd group
    int lo = xcd * (N_NODES / 8), hi = lo + (N_NODES / 8);
    int tid = gb * 256 + threadIdx.x;  // 0..32767 within group
    for (int e = tid; e < N_EDGES; e += 32768) {
        int d = dst[e];
        if (d >= lo && d < hi) {
            int p = atomicAdd(&cursor[d], 1);
            buckets[d * CAP + p] = src[e];
        }
    }
}

// ---------------------------------------------------------------------------
// fused weight cast+transpose for all three layers
// ---------------------------------------------------------------------------
__global__ __launch_bounds__(256) void wt_all_kernel(
    const float* __restrict__ Wl0, const float* __restrict__ Wr0,
    const float* __restrict__ Wl1, const float* __restrict__ Wr1,
    const float* __restrict__ Wl2, const float* __restrict__ Wr2,
    ushort* __restrict__ WT0, ushort* __restrict__ WT1,
    ushort* __restrict__ WT2l, ushort* __restrict__ WT2r) {
    int tid = blockIdx.x * 256 + threadIdx.x;
    if (tid < 32768) {
        int n = tid >> 8, k2 = tid & 255;
        float v = (k2 < 128) ? Wl0[k2 * 128 + n] : Wr0[(k2 - 128) * 128 + n];
        WT0[tid] = f2bf(v);
    } else if (tid < 65536) {
        int t = tid - 32768;
        int n = t >> 8, k2 = t & 255;
        float v = (k2 < 128) ? Wl1[k2 * 128 + n] : Wr1[(k2 - 128) * 128 + n];
        WT1[t] = f2bf(v);
    } else if (tid < 73728) {
        int t = tid - 65536;
        int n = t >> 7, k = t & 127;
        WT2l[t] = f2bf(Wl2[k * 64 + n]);
    } else if (tid < 81920) {
        int t = tid - 73728;
        int n = t >> 7, k = t & 127;
        WT2r[t] = f2bf(Wr2[k * 64 + n]);
    }
}

// ---------------------------------------------------------------------------
// cast x (fp32 [N][128]) -> bf16 into cat buffer cols 128:256
// ---------------------------------------------------------------------------
__global__ __launch_bounds__(256) void cast_x_kernel(const float* __restrict__ x,
                                                     uint* __restrict__ buf) {
    uint tid = blockIdx.x * 256 + threadIdx.x;
    if (tid >= (uint)N_NODES * 64) return;
    uint row = tid >> 6, c = tid & 63;
    float2 v = *(const float2*)(x + row * 128u + c * 2u);
    buf[row * 128u + 64u + c] = (uint)f2bf(v.x) | ((uint)f2bf(v.y) << 16);
}

// ---------------------------------------------------------------------------
// 128-ch mean aggregation — EXACT R3 version.
// ---------------------------------------------------------------------------
__global__ __launch_bounds__(256) void aggregate_kernel(
    const uint* __restrict__ Xu, const int* __restrict__ deg,
    const int* __restrict__ buckets, uint* __restrict__ Ou) {
    int node = blockIdx.x * 4 + (threadIdx.x >> 6);
    if (node >= N_NODES) return;
    int lane = threadIdx.x & 63;
    int idx = buckets[node * CAP + lane];
    int d = deg[node];
    float sx = 0.f, sy = 0.f;
    int e = 0;
    for (; e + 3 < d; e += 4) {
        int s0 = __shfl(idx, e, 64);
        int s1 = __shfl(idx, e + 1, 64);
        int s2 = __shfl(idx, e + 2, 64);
        int s3 = __shfl(idx, e + 3, 64);
        uint u0 = Xu[(uint)s0 * 128u + 64u + lane];
        uint u1 = Xu[(uint)s1 * 128u + 64u + lane];
        uint u2 = Xu[(uint)s2 * 128u + 64u + lane];
        uint u3 = Xu[(uint)s3 * 128u + 64u + lane];
        sx += (bflo(u0) + bflo(u1)) + (bflo(u2) + bflo(u3));
        sy += (bfhi(u0) + bfhi(u1)) + (bfhi(u2) + bfhi(u3));
    }
    for (; e < d; e++) {
        int s0 = __shfl(idx, e, 64);
        uint u0 = Xu[(uint)s0 * 128u + 64u + lane];
        sx += bflo(u0);
        sy += bfhi(u0);
    }
    float inv = 1.0f / (float)(d > 0 ? d : 1);
    sx *= inv;
    sy *= inv;
    Ou[(uint)node * 128u + lane] = (uint)f2bf(sx) | ((uint)f2bf(sy) << 16);
}

// ---------------------------------------------------------------------------
// 64-ch mean aggregation (layer-2 transform-first) — EXACT R3 version.
// ---------------------------------------------------------------------------
__global__ __launch_bounds__(256) void aggregate64_kernel(
    const ushort* __restrict__ T2, const int* __restrict__ deg,
    const int* __restrict__ buckets, ushort* __restrict__ A64) {
    int node = blockIdx.x * 4 + (threadIdx.x >> 6);
    if (node >= N_NODES) return;
    int lane = threadIdx.x & 63;
    int idx = buckets[node * CAP + lane];
    int d = deg[node];
    int half = lane >> 5, c = lane & 31;
    const uint* T2u = (const uint*)T2;
    float sx = 0.f, sy = 0.f;
    for (int e = half; e < d; e += 2) {
        int s = __shfl(idx, e, 64);
        uint u = T2u[(uint)s * 32u + c];
        sx += bflo(u);
        sy += bfhi(u);
    }
    sx += __shfl_xor(sx, 32, 64);
    sy += __shfl_xor(sy, 32, 64);
    if (half == 0) {
        float inv = 1.0f / (float)(d > 0 ? d : 1);
        ((uint*)A64)[(uint)node * 32u + c] =
            (uint)f2bf(sx * inv) | ((uint)f2bf(sy * inv) << 16);
    }
}

// ---------------------------------------------------------------------------
// MFMA GEMM over the cat buffer. A rows: Ain + row*256 + AOFF, K = KLEN.
// B (weights [NOUT][KLEN]) in LDS, 16B chunks XOR-swizzled by (row&7).
// MODE 0: bf16 -> next cat buffer h-part; MODE 1: bf16 compact [N][NOUT];
// MODE 2: fp32 out + bias + bf16 addend (agg64)
// ---------------------------------------------------------------------------
template <int NOUT, int KLEN, bool RELU, int MODE>
__global__ __launch_bounds__(256, 1) void mm_mfma_kernel(
    const ushort* __restrict__ Ain, const ushort* __restrict__ WT,
    const float* __restrict__ bias, ushort* __restrict__ Ybf,
    float* __restrict__ Yf, const ushort* __restrict__ Abf) {
    constexpr int NFRAG = NOUT / 64;
    constexpr int AOFF = (KLEN == 128) ? 128 : 0;
    constexpr int CPR = KLEN / 8;
    __shared__ ushort sW[NOUT * KLEN];

    int t = threadIdx.x;
    {
        constexpr int CH = NOUT * CPR;
        const uint4* s4 = (const uint4*)WT;
        #pragma unroll
        for (int c = t; c < CH; c += 256) {
            int row = c / CPR, cc = c % CPR;
            *(uint4*)&sW[(uint)row * KLEN + (uint)((cc ^ (row & 7)) << 3)] = s4[c];
        }
    }
    __syncthreads();

    int wave = t >> 6, lane = t & 63;
    uint m0 = blockIdx.x * 128u;
    int nbase = wave * (NOUT / 4);
    int lrow = lane & 15, lq = lane >> 4;

    f32x4 acc[8][NFRAG] = {};

    const ushort* aptr[8];
    #pragma unroll
    for (int mf = 0; mf < 8; mf++) {
        uint r = m0 + mf * 16 + lrow;
        if (r > N_NODES - 1) r = N_NODES - 1;
        aptr[mf] = Ain + r * 256u + AOFF + (uint)(lq * 8);
    }
    uint nrow[NFRAG], nx7[NFRAG];
    #pragma unroll
    for (int nf = 0; nf < NFRAG; nf++) {
        nrow[nf] = (uint)(nbase + nf * 16 + lrow);
        nx7[nf] = nrow[nf] & 7u;
    }

    #pragma unroll
    for (int kk = 0; kk < KLEN / 32; kk++) {
        bf16x8 bfr[NFRAG];
        #pragma unroll
        for (int nf = 0; nf < NFRAG; nf++) {
            uint phys = ((uint)(kk * 4 + lq)) ^ nx7[nf];
            bfr[nf] = *(const bf16x8*)&sW[nrow[nf] * (uint)KLEN + phys * 8u];
        }
        #pragma unroll
        for (int mf = 0; mf < 8; mf++) {
            bf16x8 afr = *(const bf16x8*)(aptr[mf] + kk * 32);
            #pragma unroll
            for (int nf = 0; nf < NFRAG; nf++)
                acc[mf][nf] = __builtin_amdgcn_mfma_f32_16x16x32_bf16(afr, bfr[nf],
                                                                      acc[mf][nf], 0, 0, 0);
        }
    }

    #pragma unroll
    for (int nf = 0; nf < NFRAG; nf++) {
        int col = nbase + nf * 16 + lrow;
        float bv = bias ? bias[col] : 0.f;
        #pragma unroll
        for (int mf = 0; mf < 8; mf++) {
            uint rowb = m0 + mf * 16 + lq * 4;
            #pragma unroll
            for (int r = 0; r < 4; r++) {
                uint row = rowb + r;
                if (row < N_NODES) {
                    float v = acc[mf][nf][r] + bv;
                    if (RELU) v = fmaxf(v, 0.f);
                    if (MODE == 0)
                        Ybf[row * 256u + 128u + (uint)col] = f2bf(v);
                    else if (MODE == 1)
                        Ybf[row * (uint)NOUT + (uint)col] = f2bf(v);
                    else
                        Yf[row * (uint)NOUT + (uint)col] =
                            v + bflo((uint)Abf[row * (uint)NOUT + (uint)col]);
                }
            }
        }
    }
}

// ---------------------------------------------------------------------------
extern "C" void kernel_launch(void* const* d_in, const int* in_sizes, int n_in,
                              void* d_out, int out_size, void* d_ws, size_t ws_size,
                              hipStream_t stream) {
    const float* x   = (const float*)d_in[0];
    const int*   src = (const int*)d_in[1];
    const int*   dst = (const int*)d_in[2];
    const float* Wl0 = (const float*)d_in[3];
    const float* bl0 = (const float*)d_in[4];
    const float* Wr0 = (const float*)d_in[5];
    const float* Wl1 = (const float*)d_in[6];
    const float* bl1 = (const float*)d_in[7];
    const float* Wr1 = (const float*)d_in[8];
    const float* Wl2 = (const float*)d_in[9];
    const float* bl2 = (const float*)d_in[10];
    const float* Wr2 = (const float*)d_in[11];
    float* out = (float*)d_out;

    char* w = (char*)d_ws;
    auto alloc = [&](size_t bytes) {
        char* p = w;
        w += (bytes + 255) & ~(size_t)255;
        return p;
    };
    int*    cursor  = (int*)alloc(N_NODES * sizeof(int));  // -> degree
    int*    buckets = (int*)alloc((size_t)N_NODES * CAP * sizeof(int));
    uint*   buf0    = (uint*)alloc((size_t)N_NODES * 128 * sizeof(uint));  // [agg|h]
    uint*   buf1    = (uint*)alloc((size_t)N_NODES * 128 * sizeof(uint));
    ushort* t2      = (ushort*)alloc((size_t)N_NODES * 64 * sizeof(ushort));
    ushort* a64     = (ushort*)alloc((size_t)N_NODES * 64 * sizeof(ushort));
    ushort* WT0     = (ushort*)alloc(128 * 256 * sizeof(ushort));
    ushort* WT1     = (ushort*)alloc(128 * 256 * sizeof(ushort));
    ushort* WT2l    = (ushort*)alloc(64 * 128 * sizeof(ushort));
    ushort* WT2r    = (ushort*)alloc(64 * 128 * sizeof(ushort));

    // --- graph buckets ---
    (void)hipMemsetAsync(cursor, 0, N_NODES * sizeof(int), stream);
    bucket_fill_kernel<<<1024, 256, 0, stream>>>(src, dst, cursor, buckets);

    // --- weight prep + x cast ---
    wt_all_kernel<<<320, 256, 0, stream>>>(Wl0, Wr0, Wl1, Wr1, Wl2, Wr2,
                                           WT0, WT1, WT2l, WT2r);
    cast_x_kernel<<<(N_NODES * 64 + 255) / 256, 256, 0, stream>>>(x, buf0);

    int ab = (N_NODES + 3) / 4;
    int mb = (N_NODES + 127) / 128;
    // --- layer 0 ---
    aggregate_kernel<<<ab, 256, 0, stream>>>(buf0, cursor, buckets, buf0);
    mm_mfma_kernel<128, 256, true, 0><<<mb, 256, 0, stream>>>(
        (const ushort*)buf0, WT0, bl0, (ushort*)buf1, nullptr, nullptr);
    // --- layer 1 ---
    aggregate_kernel<<<ab, 256, 0, stream>>>(buf1, cursor, buckets, buf1);
    mm_mfma_kernel<128, 256, true, 0><<<mb, 256, 0, stream>>>(
        (const ushort*)buf1, WT1, bl1, (ushort*)buf0, nullptr, nullptr);
    // --- layer 2: transform-first (mean is linear) ---
    mm_mfma_kernel<64, 128, false, 1><<<mb, 256, 0, stream>>>(
        (const ushort*)buf0, WT2l, nullptr, t2, nullptr, nullptr);
    aggregate64_kernel<<<ab, 256, 0, stream>>>(t2, cursor, buckets, a64);
    mm_mfma_kernel<64, 128, false, 2><<<mb, 256, 0, stream>>>(
        (const ushort*)buf0, WT2r, bl2, nullptr, out, a64);
}